// Round 2
// baseline (2457.302 us; speedup 1.0000x reference)
//
#include <hip/hip_runtime.h>
#include <hip/hip_bf16.h>

#define NTX    100000
#define NADDR  200000
#define NEDGE  400000
#define FTX    165
#define HDIM   256
#define NEG_SLOPE 0.2f
#define LN_EPS 1e-5f

typedef __hip_bfloat16 bf16;

__device__ __forceinline__ float to_f(float x) { return x; }
__device__ __forceinline__ float to_f(bf16 x) { return __bfloat162float(x); }
__device__ __forceinline__ void from_f(float x, float& o) { o = x; }
__device__ __forceinline__ void from_f(float x, bf16& o) { o = __float2bfloat16(x); }

__device__ __forceinline__ float4 load_bf16x4(const bf16* p) {
    const __hip_bfloat162* q = (const __hip_bfloat162*)p;
    __hip_bfloat162 v0 = q[0], v1 = q[1];
    return make_float4(__bfloat162float(v0.x), __bfloat162float(v0.y),
                       __bfloat162float(v1.x), __bfloat162float(v1.y));
}
__device__ __forceinline__ void store_bf16x4(bf16* p, float4 v) {
    __hip_bfloat162* q = (__hip_bfloat162*)p;
    __hip_bfloat162 t0, t1;
    t0.x = __float2bfloat16(v.x); t0.y = __float2bfloat16(v.y);
    t1.x = __float2bfloat16(v.z); t1.y = __float2bfloat16(v.w);
    q[0] = t0; q[1] = t1;
}

// ---------------------------------------------------------------------------
// C[M,N] = A[M,K] @ B[K,N] (+bias). 64x64 tile, BK=16, 256 thr, 4x4 microtile.
// ---------------------------------------------------------------------------
template<typename TA, typename TC>
__global__ __launch_bounds__(256) void gemm_t(
    const TA* __restrict__ A, const float* __restrict__ B,
    const float* __restrict__ bias, TC* __restrict__ C,
    int M, int N, int K)
{
    __shared__ float As[16][64];
    __shared__ float Bs[16][64];
    const int t = threadIdx.x;
    const int row0 = blockIdx.x * 64;
    const int col0 = blockIdx.y * 64;
    const int tm = t >> 4, tn = t & 15;
    float acc[4][4] = {};
    for (int k0 = 0; k0 < K; k0 += 16) {
#pragma unroll
        for (int i = 0; i < 4; ++i) {
            int idx = t + 256 * i;
            int m = idx >> 4, kk = idx & 15;
            int r = row0 + m, c = k0 + kk;
            As[kk][m] = (r < M && c < K) ? to_f(A[(size_t)r * K + c]) : 0.f;
        }
#pragma unroll
        for (int i = 0; i < 4; ++i) {
            int idx = t + 256 * i;
            int kk = idx >> 6, n = idx & 63;
            int r = k0 + kk;
            Bs[kk][n] = (r < K) ? B[(size_t)r * N + col0 + n] : 0.f;
        }
        __syncthreads();
#pragma unroll
        for (int kk = 0; kk < 16; ++kk) {
            const float4 a4 = *(const float4*)&As[kk][tm * 4];
            const float4 b4 = *(const float4*)&Bs[kk][tn * 4];
            float a_[4] = {a4.x, a4.y, a4.z, a4.w};
            float b_[4] = {b4.x, b4.y, b4.z, b4.w};
#pragma unroll
            for (int i = 0; i < 4; ++i)
#pragma unroll
                for (int j = 0; j < 4; ++j)
                    acc[i][j] += a_[i] * b_[j];
        }
        __syncthreads();
    }
    float4 bv = make_float4(0.f, 0.f, 0.f, 0.f);
    if (bias) bv = *(const float4*)&bias[col0 + tn * 4];
#pragma unroll
    for (int i = 0; i < 4; ++i) {
        int r = row0 + tm * 4 + i;
        if (r < M) {
            TC* cp = &C[(size_t)r * N + col0 + tn * 4];
            from_f(acc[i][0] + bv.x, cp[0]);
            from_f(acc[i][1] + bv.y, cp[1]);
            from_f(acc[i][2] + bv.z, cp[2]);
            from_f(acc[i][3] + bv.w, cp[3]);
        }
    }
}

// ---------------------------------------------------------------------------
// Vd[k,h] = sum_j W[k, h*64+j] * a_d[h,j]
// ---------------------------------------------------------------------------
__global__ void build_vd(const float* __restrict__ W, const float* __restrict__ a_d,
                         float* __restrict__ Vd, int K)
{
    int idx = blockIdx.x * blockDim.x + threadIdx.x;  // k*4+h
    if (idx >= K * 4) return;
    int k = idx >> 2, h = idx & 3;
    float d = 0.f;
    for (int j = 0; j < 64; ++j)
        d += W[(size_t)k * HDIM + h * 64 + j] * a_d[h * 64 + j];
    Vd[idx] = d;
}

// ---------------------------------------------------------------------------
// al_dst[n,h] = sum_k X[n,k] * V[k,h].  Wave per row, X bf16.
// ---------------------------------------------------------------------------
__global__ __launch_bounds__(256) void attn_dst(
    const bf16* __restrict__ X, const float* __restrict__ V,
    float* __restrict__ out, int M, int K)
{
    int n = (blockIdx.x * 256 + threadIdx.x) >> 6;
    int lane = threadIdx.x & 63;
    if (n >= M) return;
    const bf16* xr = X + (size_t)n * K;
    float a0 = 0.f, a1 = 0.f, a2 = 0.f, a3 = 0.f;
    for (int k = lane; k < K; k += 64) {
        float xv = to_f(xr[k]);
        a0 += xv * V[k * 4 + 0];
        a1 += xv * V[k * 4 + 1];
        a2 += xv * V[k * 4 + 2];
        a3 += xv * V[k * 4 + 3];
    }
#pragma unroll
    for (int off = 32; off; off >>= 1) {
        a0 += __shfl_xor(a0, off); a1 += __shfl_xor(a1, off);
        a2 += __shfl_xor(a2, off); a3 += __shfl_xor(a3, off);
    }
    if (lane == 0) {
        out[(size_t)n * 4 + 0] = a0; out[(size_t)n * 4 + 1] = a1;
        out[(size_t)n * 4 + 2] = a2; out[(size_t)n * 4 + 3] = a3;
    }
}

// ---------------------------------------------------------------------------
// al_src[n,h] = sum_j hs[n, h*64+j] * a_s[h,j].  Wave per row (hs 256-wide).
// ---------------------------------------------------------------------------
__global__ __launch_bounds__(256) void attn_src(
    const bf16* __restrict__ hs, const float* __restrict__ a_s,
    float* __restrict__ out, int M)
{
    int n = (blockIdx.x * 256 + threadIdx.x) >> 6;
    int lane = threadIdx.x & 63;
    if (n >= M) return;
    float4 v = load_bf16x4(hs + (size_t)n * HDIM + lane * 4);
    float4 a = *(const float4*)&a_s[lane * 4];   // a_s[4][64] flat matches lane*4
    float s = v.x * a.x + v.y * a.y + v.z * a.z + v.w * a.w;
#pragma unroll
    for (int off = 1; off < 16; off <<= 1) s += __shfl_xor(s, off);
    if ((lane & 15) == 0) out[(size_t)n * 4 + (lane >> 4)] = s;
}

// ---------------------------------------------------------------------------
// CSR build: histogram, 3-phase exclusive scan, scatter.
// ---------------------------------------------------------------------------
__global__ void k_hist(const int* __restrict__ dst, int* __restrict__ deg, int E)
{
    int e = blockIdx.x * blockDim.x + threadIdx.x;
    if (e < E) atomicAdd(&deg[dst[e]], 1);
}

__global__ void scan_partial(const int* __restrict__ deg, int* __restrict__ bsum, int N)
{
    __shared__ int lds[256];
    int base = blockIdx.x * 1024, t = threadIdx.x;
    int s = 0;
#pragma unroll
    for (int i = 0; i < 4; ++i) {
        int idx = base + t * 4 + i;
        if (idx < N) s += deg[idx];
    }
    lds[t] = s; __syncthreads();
    for (int off = 128; off; off >>= 1) {
        if (t < off) lds[t] += lds[t + off];
        __syncthreads();
    }
    if (t == 0) bsum[blockIdx.x] = lds[0];
}

__global__ void scan_bsum(int* __restrict__ bsum, int NB, int* __restrict__ rp, int N, int E)
{
    if (threadIdx.x == 0 && blockIdx.x == 0) {
        int acc = 0;
        for (int b = 0; b < NB; ++b) { int v = bsum[b]; bsum[b] = acc; acc += v; }
        rp[N] = E;
    }
}

__global__ void scan_write(const int* __restrict__ deg, const int* __restrict__ bsum,
                           int* __restrict__ rp, int N)
{
    __shared__ int lds[256];
    int base = blockIdx.x * 1024, t = threadIdx.x;
    int v[4]; int s = 0;
#pragma unroll
    for (int i = 0; i < 4; ++i) {
        int idx = base + t * 4 + i;
        v[i] = (idx < N) ? deg[idx] : 0;
        s += v[i];
    }
    lds[t] = s; __syncthreads();
    for (int off = 1; off < 256; off <<= 1) {
        int x = (t >= off) ? lds[t - off] : 0;
        __syncthreads();
        lds[t] += x;
        __syncthreads();
    }
    int excl = lds[t] - s + bsum[blockIdx.x];
#pragma unroll
    for (int i = 0; i < 4; ++i) {
        int idx = base + t * 4 + i;
        if (idx < N) rp[idx] = excl;
        excl += v[i];
    }
}

__global__ void k_scatter(const int* __restrict__ dst, const int* __restrict__ rp,
                          int* __restrict__ cur, int* __restrict__ perm, int E)
{
    int e = blockIdx.x * blockDim.x + threadIdx.x;
    if (e >= E) return;
    int d = dst[e];
    int pos = atomicAdd(&cur[d], 1);
    perm[rp[d] + pos] = e;
}

// ---------------------------------------------------------------------------
// Fused per-dst-node: online softmax-weighted sum over incoming edges (CSR),
// + bias, LayerNorm, (+residual), ELU -> h_out (bf16). Wave per node.
// ---------------------------------------------------------------------------
__global__ __launch_bounds__(256) void aggregate_ln_elu(
    const int* __restrict__ rp, const int* __restrict__ perm,
    const int* __restrict__ src_idx,
    const float* __restrict__ al_src, const float* __restrict__ al_dst,
    const bf16* __restrict__ hs,
    const float* __restrict__ bias, const float* __restrict__ g,
    const float* __restrict__ b,
    const bf16* __restrict__ res, bf16* __restrict__ h_out, int n_dst)
{
    int d = (blockIdx.x * 256 + threadIdx.x) >> 6;
    int lane = threadIdx.x & 63;
    if (d >= n_dst) return;
    int head = lane >> 4;
    float ad = al_dst[(size_t)d * 4 + head];
    int beg = rp[d], end = rp[d + 1];
    float acc0 = 0.f, acc1 = 0.f, acc2 = 0.f, acc3 = 0.f, den = 0.f;
    for (int i = beg; i < end; ++i) {
        int e = perm[i];
        int s = src_idx[e];
        float al = al_src[(size_t)s * 4 + head] + ad;
        al = al >= 0.f ? al : NEG_SLOPE * al;
        float ex = expf(al);
        den += ex;
        float4 v = load_bf16x4(hs + (size_t)s * HDIM + lane * 4);
        acc0 += ex * v.x; acc1 += ex * v.y; acc2 += ex * v.z; acc3 += ex * v.w;
    }
    float inv = den > 0.f ? 1.f / den : 0.f;
    float4 bi = *(const float4*)&bias[lane * 4];
    float x0 = acc0 * inv + bi.x, x1 = acc1 * inv + bi.y;
    float x2 = acc2 * inv + bi.z, x3 = acc3 * inv + bi.w;
    float sum = x0 + x1 + x2 + x3;
#pragma unroll
    for (int off = 32; off; off >>= 1) sum += __shfl_xor(sum, off);
    float mu = sum * (1.f / 256.f);
    float d0 = x0 - mu, d1 = x1 - mu, d2 = x2 - mu, d3 = x3 - mu;
    float sq = d0 * d0 + d1 * d1 + d2 * d2 + d3 * d3;
#pragma unroll
    for (int off = 32; off; off >>= 1) sq += __shfl_xor(sq, off);
    float rstd = rsqrtf(sq * (1.f / 256.f) + LN_EPS);
    float4 gg = *(const float4*)&g[lane * 4];
    float4 bb = *(const float4*)&b[lane * 4];
    float y0 = d0 * rstd * gg.x + bb.x;
    float y1 = d1 * rstd * gg.y + bb.y;
    float y2 = d2 * rstd * gg.z + bb.z;
    float y3 = d3 * rstd * gg.w + bb.w;
    if (res) {
        float4 r4 = load_bf16x4(res + (size_t)d * HDIM + lane * 4);
        y0 += r4.x; y1 += r4.y; y2 += r4.z; y3 += r4.w;
    }
    float4 o;
    o.x = y0 > 0.f ? y0 : expm1f(y0);
    o.y = y1 > 0.f ? y1 : expm1f(y1);
    o.z = y2 > 0.f ? y2 : expm1f(y2);
    o.w = y3 > 0.f ? y3 : expm1f(y3);
    store_bf16x4(h_out + (size_t)d * HDIM + lane * 4, o);
}

// ---------------------------------------------------------------------------
// Pool: mean over incoming at-edges of h_addr -> pooled (bf16). Wave per node.
// ---------------------------------------------------------------------------
__global__ __launch_bounds__(256) void k_pool(
    const int* __restrict__ rp, const int* __restrict__ perm,
    const int* __restrict__ src_idx, const bf16* __restrict__ h,
    bf16* __restrict__ out, int n_dst)
{
    int d = (blockIdx.x * 256 + threadIdx.x) >> 6;
    int lane = threadIdx.x & 63;
    if (d >= n_dst) return;
    int beg = rp[d], end = rp[d + 1];
    float a0 = 0.f, a1 = 0.f, a2 = 0.f, a3 = 0.f;
    for (int i = beg; i < end; ++i) {
        int s = src_idx[perm[i]];
        float4 v = load_bf16x4(h + (size_t)s * HDIM + lane * 4);
        a0 += v.x; a1 += v.y; a2 += v.z; a3 += v.w;
    }
    float c = 1.f / (float)max(end - beg, 1);
    store_bf16x4(out + (size_t)d * HDIM + lane * 4,
                 make_float4(a0 * c, a1 * c, a2 * c, a3 * c));
}

// ---------------------------------------------------------------------------
extern "C" void kernel_launch(void* const* d_in, const int* in_sizes, int n_in,
                              void* d_out, int out_size, void* d_ws, size_t ws_size,
                              hipStream_t stream)
{
    const float* x_tx      = (const float*)d_in[0];
    const float* x_addr    = (const float*)d_in[1];
    const int* addr_idx_at = (const int*)d_in[2];
    const int* tx_idx_at   = (const int*)d_in[3];
    const int* tx_idx_ta   = (const int*)d_in[4];
    const int* addr_idx_ta = (const int*)d_in[5];
    const float* w_in_tx   = (const float*)d_in[6];
    const float* b_in_tx   = (const float*)d_in[7];
    const float* w_in_addr = (const float*)d_in[8];
    const float* b_in_addr = (const float*)d_in[9];
    const float* w_at[2]  = {(const float*)d_in[10], (const float*)d_in[18]};
    const float* as_at[2] = {(const float*)d_in[11], (const float*)d_in[19]};
    const float* ad_at[2] = {(const float*)d_in[12], (const float*)d_in[20]};
    const float* b_at[2]  = {(const float*)d_in[13], (const float*)d_in[21]};
    const float* w_ta[2]  = {(const float*)d_in[14], (const float*)d_in[22]};
    const float* as_ta[2] = {(const float*)d_in[15], (const float*)d_in[23]};
    const float* ad_ta[2] = {(const float*)d_in[16], (const float*)d_in[24]};
    const float* b_ta[2]  = {(const float*)d_in[17], (const float*)d_in[25]};
    const float* ln_g_tx   = (const float*)d_in[26];
    const float* ln_b_tx   = (const float*)d_in[27];
    const float* ln_g_addr = (const float*)d_in[28];
    const float* ln_b_addr = (const float*)d_in[29];
    const float* w_out     = (const float*)d_in[30];
    const float* b_out     = (const float*)d_in[31];

    // ---- workspace carve-out (256B aligned), total ~365 MB ----
    char* p = (char*)d_ws;
    auto alloc = [&](size_t bytes) -> void* {
        void* r = (void*)p; p += (bytes + 255) & ~(size_t)255; return r;
    };
    bf16* h0_tx   = (bf16*)alloc((size_t)NTX * 64 * 2);
    bf16* h0_addr = (bf16*)alloc((size_t)NADDR * 64 * 2);
    bf16* h_tx    = (bf16*)alloc((size_t)NTX * HDIM * 2);
    bf16* h_addr  = (bf16*)alloc((size_t)NADDR * HDIM * 2);
    bf16* hs_a    = (bf16*)alloc((size_t)NADDR * HDIM * 2);
    bf16* hs_t    = (bf16*)alloc((size_t)NTX * HDIM * 2);   // also pooled buffer
    float* al_src_at = (float*)alloc((size_t)NADDR * 4 * 4);
    float* al_dst_at = (float*)alloc((size_t)NTX * 4 * 4);
    float* al_src_ta = (float*)alloc((size_t)NTX * 4 * 4);
    float* al_dst_ta = (float*)alloc((size_t)NADDR * 4 * 4);
    float* Vd_at  = (float*)alloc(HDIM * 4 * 4);
    float* Vd_ta  = (float*)alloc(HDIM * 4 * 4);
    int* rp_at    = (int*)alloc((size_t)(NTX + 1) * 4);
    int* rp_ta    = (int*)alloc((size_t)(NADDR + 1) * 4);
    int* perm_at  = (int*)alloc((size_t)NEDGE * 4);
    int* perm_ta  = (int*)alloc((size_t)NEDGE * 4);
    int* deg_tx   = (int*)alloc((size_t)NTX * 4);
    int* deg_addr = (int*)alloc((size_t)NADDR * 4);
    int* cur_tx   = (int*)alloc((size_t)NTX * 4);
    int* cur_addr = (int*)alloc((size_t)NADDR * 4);
    int* bsum_tx  = (int*)alloc(1024 * 4);
    int* bsum_ad  = (int*)alloc(1024 * 4);

    dim3 blk(256);
    const int EG = (NEDGE + 255) / 256;
    auto gemm_fb = [&](const float* A, const float* B, const float* bias, bf16* C,
                       int M, int N, int K) {
        dim3 grid((M + 63) / 64, N / 64);
        hipLaunchKernelGGL((gemm_t<float, bf16>), grid, blk, 0, stream, A, B, bias, C, M, N, K);
    };
    auto gemm_bb = [&](const bf16* A, const float* B, const float* bias, bf16* C,
                       int M, int N, int K) {
        dim3 grid((M + 63) / 64, N / 64);
        hipLaunchKernelGGL((gemm_t<bf16, bf16>), grid, blk, 0, stream, A, B, bias, C, M, N, K);
    };

    // ---- CSR build for both relations ----
    hipMemsetAsync(deg_tx, 0, (size_t)NTX * 4, stream);
    hipMemsetAsync(deg_addr, 0, (size_t)NADDR * 4, stream);
    hipMemsetAsync(cur_tx, 0, (size_t)NTX * 4, stream);
    hipMemsetAsync(cur_addr, 0, (size_t)NADDR * 4, stream);
    hipLaunchKernelGGL(k_hist, dim3(EG), blk, 0, stream, tx_idx_at, deg_tx, NEDGE);
    hipLaunchKernelGGL(k_hist, dim3(EG), blk, 0, stream, addr_idx_ta, deg_addr, NEDGE);
    const int NB_tx = (NTX + 1023) / 1024, NB_ad = (NADDR + 1023) / 1024;
    hipLaunchKernelGGL(scan_partial, dim3(NB_tx), blk, 0, stream, deg_tx, bsum_tx, NTX);
    hipLaunchKernelGGL(scan_partial, dim3(NB_ad), blk, 0, stream, deg_addr, bsum_ad, NADDR);
    hipLaunchKernelGGL(scan_bsum, dim3(1), blk, 0, stream, bsum_tx, NB_tx, rp_at, NTX, NEDGE);
    hipLaunchKernelGGL(scan_bsum, dim3(1), blk, 0, stream, bsum_ad, NB_ad, rp_ta, NADDR, NEDGE);
    hipLaunchKernelGGL(scan_write, dim3(NB_tx), blk, 0, stream, deg_tx, bsum_tx, rp_at, NTX);
    hipLaunchKernelGGL(scan_write, dim3(NB_ad), blk, 0, stream, deg_addr, bsum_ad, rp_ta, NADDR);
    hipLaunchKernelGGL(k_scatter, dim3(EG), blk, 0, stream, tx_idx_at, rp_at, cur_tx, perm_at, NEDGE);
    hipLaunchKernelGGL(k_scatter, dim3(EG), blk, 0, stream, addr_idx_ta, rp_ta, cur_addr, perm_ta, NEDGE);

    // ---- input projections ----
    gemm_fb(x_tx, w_in_tx, b_in_tx, h0_tx, NTX, 64, FTX);
    gemm_fb(x_addr, w_in_addr, b_in_addr, h0_addr, NADDR, 64, 64);

    for (int layer = 0; layer < 2; ++layer) {
        const int in_dim = layer ? HDIM : 64;
        const bf16* ftx = layer ? h_tx : h0_tx;
        const bf16* fad = layer ? h_addr : h0_addr;

        // projections for both relations (before any h overwrite)
        gemm_bb(fad, w_at[layer], nullptr, hs_a, NADDR, HDIM, in_dim);
        gemm_bb(ftx, w_ta[layer], nullptr, hs_t, NTX, HDIM, in_dim);

        // attention logit halves
        hipLaunchKernelGGL(build_vd, dim3((in_dim * 4 + 255) / 256), blk, 0, stream,
                           w_at[layer], ad_at[layer], Vd_at, in_dim);
        hipLaunchKernelGGL(build_vd, dim3((in_dim * 4 + 255) / 256), blk, 0, stream,
                           w_ta[layer], ad_ta[layer], Vd_ta, in_dim);
        hipLaunchKernelGGL(attn_src, dim3((NADDR + 3) / 4), blk, 0, stream,
                           hs_a, as_at[layer], al_src_at, NADDR);
        hipLaunchKernelGGL(attn_src, dim3((NTX + 3) / 4), blk, 0, stream,
                           hs_t, as_ta[layer], al_src_ta, NTX);
        hipLaunchKernelGGL(attn_dst, dim3((NTX + 3) / 4), blk, 0, stream,
                           ftx, Vd_at, al_dst_at, NTX, in_dim);
        hipLaunchKernelGGL(attn_dst, dim3((NADDR + 3) / 4), blk, 0, stream,
                           fad, Vd_ta, al_dst_ta, NADDR, in_dim);

        // fused aggregate + bias + LN + residual + ELU (in-place h update)
        const bf16* res_tx = layer ? h_tx : nullptr;
        const bf16* res_ad = layer ? h_addr : nullptr;
        hipLaunchKernelGGL(aggregate_ln_elu, dim3((NTX + 3) / 4), blk, 0, stream,
                           rp_at, perm_at, addr_idx_at, al_src_at, al_dst_at, hs_a,
                           b_at[layer], ln_g_tx, ln_b_tx, res_tx, h_tx, NTX);
        hipLaunchKernelGGL(aggregate_ln_elu, dim3((NADDR + 3) / 4), blk, 0, stream,
                           rp_ta, perm_ta, tx_idx_ta, al_src_ta, al_dst_ta, hs_t,
                           b_ta[layer], ln_g_addr, ln_b_addr, res_ad, h_addr, NADDR);
    }

    // ---- scatter-mean pooling (reuse at-CSR) + output projection ----
    hipLaunchKernelGGL(k_pool, dim3((NTX + 3) / 4), blk, 0, stream,
                       rp_at, perm_at, addr_idx_at, h_addr, hs_t, NTX);
    {
        dim3 grid((NTX + 63) / 64, HDIM / 64);
        hipLaunchKernelGGL((gemm_t<bf16, float>), grid, blk, 0, stream,
                           hs_t, w_out, b_out, (float*)d_out, NTX, HDIM, HDIM);
    }
}

// Round 3
// 1660.403 us; speedup vs baseline: 1.4799x; 1.4799x over previous
//
#include <hip/hip_runtime.h>
#include <hip/hip_bf16.h>

#define NTX    100000
#define NADDR  200000
#define NEDGE  400000
#define FTX    165
#define HDIM   256
#define NEG_SLOPE 0.2f
#define LN_EPS 1e-5f

typedef __hip_bfloat16 bf16;
typedef __attribute__((ext_vector_type(8))) short short8;   // 8 bf16 = 4 VGPRs
typedef __attribute__((ext_vector_type(4))) float floatx4;

__device__ __forceinline__ float to_f(float x) { return x; }
__device__ __forceinline__ float to_f(bf16 x) { return __bfloat162float(x); }
__device__ __forceinline__ void from_f(float x, float& o) { o = x; }
__device__ __forceinline__ void from_f(float x, bf16& o) { o = __float2bfloat16(x); }

__device__ __forceinline__ float4 load_bf16x4(const bf16* p) {
    const __hip_bfloat162* q = (const __hip_bfloat162*)p;
    __hip_bfloat162 v0 = q[0], v1 = q[1];
    return make_float4(__bfloat162float(v0.x), __bfloat162float(v0.y),
                       __bfloat162float(v1.x), __bfloat162float(v1.y));
}
__device__ __forceinline__ void store_bf16x4(bf16* p, float4 v) {
    __hip_bfloat162* q = (__hip_bfloat162*)p;
    __hip_bfloat162 t0, t1;
    t0.x = __float2bfloat16(v.x); t0.y = __float2bfloat16(v.y);
    t1.x = __float2bfloat16(v.z); t1.y = __float2bfloat16(v.w);
    q[0] = t0; q[1] = t1;
}

// ---------------------------------------------------------------------------
// fp32 SIMD GEMM (in-projections only). 64x64 tile, BK=16, 4x4 microtile.
// ---------------------------------------------------------------------------
template<typename TA, typename TC>
__global__ __launch_bounds__(256) void gemm_t(
    const TA* __restrict__ A, const float* __restrict__ B,
    const float* __restrict__ bias, TC* __restrict__ C,
    int M, int N, int K)
{
    __shared__ float As[16][64];
    __shared__ float Bs[16][64];
    const int t = threadIdx.x;
    const int row0 = blockIdx.x * 64;
    const int col0 = blockIdx.y * 64;
    const int tm = t >> 4, tn = t & 15;
    float acc[4][4] = {};
    for (int k0 = 0; k0 < K; k0 += 16) {
#pragma unroll
        for (int i = 0; i < 4; ++i) {
            int idx = t + 256 * i;
            int m = idx >> 4, kk = idx & 15;
            int r = row0 + m, c = k0 + kk;
            As[kk][m] = (r < M && c < K) ? to_f(A[(size_t)r * K + c]) : 0.f;
        }
#pragma unroll
        for (int i = 0; i < 4; ++i) {
            int idx = t + 256 * i;
            int kk = idx >> 6, n = idx & 63;
            int r = k0 + kk;
            Bs[kk][n] = (r < K) ? B[(size_t)r * N + col0 + n] : 0.f;
        }
        __syncthreads();
#pragma unroll
        for (int kk = 0; kk < 16; ++kk) {
            const float4 a4 = *(const float4*)&As[kk][tm * 4];
            const float4 b4 = *(const float4*)&Bs[kk][tn * 4];
            float a_[4] = {a4.x, a4.y, a4.z, a4.w};
            float b_[4] = {b4.x, b4.y, b4.z, b4.w};
#pragma unroll
            for (int i = 0; i < 4; ++i)
#pragma unroll
                for (int j = 0; j < 4; ++j)
                    acc[i][j] += a_[i] * b_[j];
        }
        __syncthreads();
    }
    float4 bv = make_float4(0.f, 0.f, 0.f, 0.f);
    if (bias) bv = *(const float4*)&bias[col0 + tn * 4];
#pragma unroll
    for (int i = 0; i < 4; ++i) {
        int r = row0 + tm * 4 + i;
        if (r < M) {
            TC* cp = &C[(size_t)r * N + col0 + tn * 4];
            from_f(acc[i][0] + bv.x, cp[0]);
            from_f(acc[i][1] + bv.y, cp[1]);
            from_f(acc[i][2] + bv.z, cp[2]);
            from_f(acc[i][3] + bv.w, cp[3]);
        }
    }
}

// ---------------------------------------------------------------------------
// Wt[n,k] = bf16(W[k,n])  (one-time weight transpose+convert)
// ---------------------------------------------------------------------------
__global__ void transpose_w(const float* __restrict__ W, bf16* __restrict__ Wt,
                            int K, int N)
{
    int idx = blockIdx.x * blockDim.x + threadIdx.x;
    if (idx >= K * N) return;
    int k = idx / N, n = idx - k * N;
    Wt[(size_t)n * K + k] = __float2bfloat16(W[idx]);
}

// ---------------------------------------------------------------------------
// MFMA bf16 GEMM: C[M,N] = A[M,K] @ Wt[N,K]^T (+bias).
// 128x128 block tile, BK=32, 256 thr = 4 waves (2x2), each wave 64x64.
// mfma_f32_16x16x32_bf16: A[m=lane&15][k=quad*8+j], B[k=quad*8+j][n=lane&15],
// D[row=quad*4+r][col=lane&15]   (m89/m91-verified layouts)
// ---------------------------------------------------------------------------
template<typename TC>
__global__ __launch_bounds__(256) void gemm_mfma(
    const bf16* __restrict__ A, const bf16* __restrict__ Wt,
    const float* __restrict__ bias, TC* __restrict__ C,
    int M, int N, int K)
{
    __shared__ __align__(16) bf16 As[128][40];   // +8 pad: 2-way LDS conflicts only
    __shared__ __align__(16) bf16 Bs[128][40];
    const int t = threadIdx.x;
    const int wv = t >> 6, lane = t & 63;
    const int l15 = lane & 15, quad = lane >> 4;
    const int row0 = blockIdx.x * 128;
    const int col0 = blockIdx.y * 128;
    const int wrow = (wv >> 1) * 64, wcol = (wv & 1) * 64;

    floatx4 acc[4][4] = {};

    for (int k0 = 0; k0 < K; k0 += 32) {
        // stage A and B tiles: 128 rows x 32 k each, 16B chunks, 2 chunks/thread
#pragma unroll
        for (int i = 0; i < 2; ++i) {
            int idx = t + 256 * i;            // 0..511
            int r = idx >> 2, c = (idx & 3) * 8;
            uint4 va = make_uint4(0, 0, 0, 0);
            if (row0 + r < M) va = *(const uint4*)&A[(size_t)(row0 + r) * K + k0 + c];
            *(uint4*)&As[r][c] = va;
            uint4 vb = make_uint4(0, 0, 0, 0);
            if (col0 + r < N) vb = *(const uint4*)&Wt[(size_t)(col0 + r) * K + k0 + c];
            *(uint4*)&Bs[r][c] = vb;
        }
        __syncthreads();
        short8 af[4], bfr[4];
#pragma unroll
        for (int rb = 0; rb < 4; ++rb)
            af[rb] = *(const short8*)&As[wrow + rb * 16 + l15][quad * 8];
#pragma unroll
        for (int nb = 0; nb < 4; ++nb)
            bfr[nb] = *(const short8*)&Bs[wcol + nb * 16 + l15][quad * 8];
#pragma unroll
        for (int rb = 0; rb < 4; ++rb)
#pragma unroll
            for (int nb = 0; nb < 4; ++nb)
                acc[rb][nb] = __builtin_amdgcn_mfma_f32_16x16x32_bf16(
                    af[rb], bfr[nb], acc[rb][nb], 0, 0, 0);
        __syncthreads();
    }

#pragma unroll
    for (int rb = 0; rb < 4; ++rb)
#pragma unroll
        for (int nb = 0; nb < 4; ++nb) {
            int col = col0 + wcol + nb * 16 + l15;
            float bv = bias ? bias[col] : 0.f;
#pragma unroll
            for (int r = 0; r < 4; ++r) {
                int row = row0 + wrow + rb * 16 + quad * 4 + r;
                if (row < M)
                    from_f(acc[rb][nb][r] + bv, C[(size_t)row * N + col]);
            }
        }
}

// ---------------------------------------------------------------------------
// Vd[k,h] = sum_j W[k, h*64+j] * a_d[h,j]
// ---------------------------------------------------------------------------
__global__ void build_vd(const float* __restrict__ W, const float* __restrict__ a_d,
                         float* __restrict__ Vd, int K)
{
    int idx = blockIdx.x * blockDim.x + threadIdx.x;  // k*4+h
    if (idx >= K * 4) return;
    int k = idx >> 2, h = idx & 3;
    float d = 0.f;
    for (int j = 0; j < 64; ++j)
        d += W[(size_t)k * HDIM + h * 64 + j] * a_d[h * 64 + j];
    Vd[idx] = d;
}

// ---------------------------------------------------------------------------
// al_dst[n,h] = sum_k X[n,k] * V[k,h].  Wave per row, X bf16.
// ---------------------------------------------------------------------------
__global__ __launch_bounds__(256) void attn_dst(
    const bf16* __restrict__ X, const float* __restrict__ V,
    float* __restrict__ out, int M, int K)
{
    int n = (blockIdx.x * 256 + threadIdx.x) >> 6;
    int lane = threadIdx.x & 63;
    if (n >= M) return;
    const bf16* xr = X + (size_t)n * K;
    float a0 = 0.f, a1 = 0.f, a2 = 0.f, a3 = 0.f;
    for (int k = lane; k < K; k += 64) {
        float xv = to_f(xr[k]);
        a0 += xv * V[k * 4 + 0];
        a1 += xv * V[k * 4 + 1];
        a2 += xv * V[k * 4 + 2];
        a3 += xv * V[k * 4 + 3];
    }
#pragma unroll
    for (int off = 32; off; off >>= 1) {
        a0 += __shfl_xor(a0, off); a1 += __shfl_xor(a1, off);
        a2 += __shfl_xor(a2, off); a3 += __shfl_xor(a3, off);
    }
    if (lane == 0) {
        out[(size_t)n * 4 + 0] = a0; out[(size_t)n * 4 + 1] = a1;
        out[(size_t)n * 4 + 2] = a2; out[(size_t)n * 4 + 3] = a3;
    }
}

// ---------------------------------------------------------------------------
// al_src[n,h] = sum_j hs[n, h*64+j] * a_s[h,j].  Wave per row (hs 256-wide).
// ---------------------------------------------------------------------------
__global__ __launch_bounds__(256) void attn_src(
    const bf16* __restrict__ hs, const float* __restrict__ a_s,
    float* __restrict__ out, int M)
{
    int n = (blockIdx.x * 256 + threadIdx.x) >> 6;
    int lane = threadIdx.x & 63;
    if (n >= M) return;
    float4 v = load_bf16x4(hs + (size_t)n * HDIM + lane * 4);
    float4 a = *(const float4*)&a_s[lane * 4];
    float s = v.x * a.x + v.y * a.y + v.z * a.z + v.w * a.w;
#pragma unroll
    for (int off = 1; off < 16; off <<= 1) s += __shfl_xor(s, off);
    if ((lane & 15) == 0) out[(size_t)n * 4 + (lane >> 4)] = s;
}

// ---------------------------------------------------------------------------
// CSR build: histogram, 3-phase exclusive scan, scatter.
// ---------------------------------------------------------------------------
__global__ void k_hist(const int* __restrict__ dst, int* __restrict__ deg, int E)
{
    int e = blockIdx.x * blockDim.x + threadIdx.x;
    if (e < E) atomicAdd(&deg[dst[e]], 1);
}

__global__ void scan_partial(const int* __restrict__ deg, int* __restrict__ bsum, int N)
{
    __shared__ int lds[256];
    int base = blockIdx.x * 1024, t = threadIdx.x;
    int s = 0;
#pragma unroll
    for (int i = 0; i < 4; ++i) {
        int idx = base + t * 4 + i;
        if (idx < N) s += deg[idx];
    }
    lds[t] = s; __syncthreads();
    for (int off = 128; off; off >>= 1) {
        if (t < off) lds[t] += lds[t + off];
        __syncthreads();
    }
    if (t == 0) bsum[blockIdx.x] = lds[0];
}

__global__ void scan_bsum(int* __restrict__ bsum, int NB, int* __restrict__ rp, int N, int E)
{
    if (threadIdx.x == 0 && blockIdx.x == 0) {
        int acc = 0;
        for (int b = 0; b < NB; ++b) { int v = bsum[b]; bsum[b] = acc; acc += v; }
        rp[N] = E;
    }
}

__global__ void scan_write(const int* __restrict__ deg, const int* __restrict__ bsum,
                           int* __restrict__ rp, int N)
{
    __shared__ int lds[256];
    int base = blockIdx.x * 1024, t = threadIdx.x;
    int v[4]; int s = 0;
#pragma unroll
    for (int i = 0; i < 4; ++i) {
        int idx = base + t * 4 + i;
        v[i] = (idx < N) ? deg[idx] : 0;
        s += v[i];
    }
    lds[t] = s; __syncthreads();
    for (int off = 1; off < 256; off <<= 1) {
        int x = (t >= off) ? lds[t - off] : 0;
        __syncthreads();
        lds[t] += x;
        __syncthreads();
    }
    int excl = lds[t] - s + bsum[blockIdx.x];
#pragma unroll
    for (int i = 0; i < 4; ++i) {
        int idx = base + t * 4 + i;
        if (idx < N) rp[idx] = excl;
        excl += v[i];
    }
}

__global__ void k_scatter(const int* __restrict__ dst, const int* __restrict__ rp,
                          int* __restrict__ cur, int* __restrict__ perm, int E)
{
    int e = blockIdx.x * blockDim.x + threadIdx.x;
    if (e >= E) return;
    int d = dst[e];
    int pos = atomicAdd(&cur[d], 1);
    perm[rp[d] + pos] = e;
}

// ---------------------------------------------------------------------------
// Fused per-dst-node: online softmax-weighted sum over incoming edges (CSR),
// + bias, LayerNorm, (+residual), ELU -> h_out (bf16). Wave per node.
// ---------------------------------------------------------------------------
__global__ __launch_bounds__(256) void aggregate_ln_elu(
    const int* __restrict__ rp, const int* __restrict__ perm,
    const int* __restrict__ src_idx,
    const float* __restrict__ al_src, const float* __restrict__ al_dst,
    const bf16* __restrict__ hs,
    const float* __restrict__ bias, const float* __restrict__ g,
    const float* __restrict__ b,
    const bf16* __restrict__ res, bf16* __restrict__ h_out, int n_dst)
{
    int d = (blockIdx.x * 256 + threadIdx.x) >> 6;
    int lane = threadIdx.x & 63;
    if (d >= n_dst) return;
    int head = lane >> 4;
    float ad = al_dst[(size_t)d * 4 + head];
    int beg = rp[d], end = rp[d + 1];
    float acc0 = 0.f, acc1 = 0.f, acc2 = 0.f, acc3 = 0.f, den = 0.f;
    for (int i = beg; i < end; ++i) {
        int e = perm[i];
        int s = src_idx[e];
        float al = al_src[(size_t)s * 4 + head] + ad;
        al = al >= 0.f ? al : NEG_SLOPE * al;
        float ex = expf(al);
        den += ex;
        float4 v = load_bf16x4(hs + (size_t)s * HDIM + lane * 4);
        acc0 += ex * v.x; acc1 += ex * v.y; acc2 += ex * v.z; acc3 += ex * v.w;
    }
    float inv = den > 0.f ? 1.f / den : 0.f;
    float4 bi = *(const float4*)&bias[lane * 4];
    float x0 = acc0 * inv + bi.x, x1 = acc1 * inv + bi.y;
    float x2 = acc2 * inv + bi.z, x3 = acc3 * inv + bi.w;
    float sum = x0 + x1 + x2 + x3;
#pragma unroll
    for (int off = 32; off; off >>= 1) sum += __shfl_xor(sum, off);
    float mu = sum * (1.f / 256.f);
    float d0 = x0 - mu, d1 = x1 - mu, d2 = x2 - mu, d3 = x3 - mu;
    float sq = d0 * d0 + d1 * d1 + d2 * d2 + d3 * d3;
#pragma unroll
    for (int off = 32; off; off >>= 1) sq += __shfl_xor(sq, off);
    float rstd = rsqrtf(sq * (1.f / 256.f) + LN_EPS);
    float4 gg = *(const float4*)&g[lane * 4];
    float4 bb = *(const float4*)&b[lane * 4];
    float y0 = d0 * rstd * gg.x + bb.x;
    float y1 = d1 * rstd * gg.y + bb.y;
    float y2 = d2 * rstd * gg.z + bb.z;
    float y3 = d3 * rstd * gg.w + bb.w;
    if (res) {
        float4 r4 = load_bf16x4(res + (size_t)d * HDIM + lane * 4);
        y0 += r4.x; y1 += r4.y; y2 += r4.z; y3 += r4.w;
    }
    float4 o;
    o.x = y0 > 0.f ? y0 : expm1f(y0);
    o.y = y1 > 0.f ? y1 : expm1f(y1);
    o.z = y2 > 0.f ? y2 : expm1f(y2);
    o.w = y3 > 0.f ? y3 : expm1f(y3);
    store_bf16x4(h_out + (size_t)d * HDIM + lane * 4, o);
}

// ---------------------------------------------------------------------------
// Pool: mean over incoming at-edges of h_addr -> pooled (bf16). Wave per node.
// ---------------------------------------------------------------------------
__global__ __launch_bounds__(256) void k_pool(
    const int* __restrict__ rp, const int* __restrict__ perm,
    const int* __restrict__ src_idx, const bf16* __restrict__ h,
    bf16* __restrict__ out, int n_dst)
{
    int d = (blockIdx.x * 256 + threadIdx.x) >> 6;
    int lane = threadIdx.x & 63;
    if (d >= n_dst) return;
    int beg = rp[d], end = rp[d + 1];
    float a0 = 0.f, a1 = 0.f, a2 = 0.f, a3 = 0.f;
    for (int i = beg; i < end; ++i) {
        int s = src_idx[perm[i]];
        float4 v = load_bf16x4(h + (size_t)s * HDIM + lane * 4);
        a0 += v.x; a1 += v.y; a2 += v.z; a3 += v.w;
    }
    float c = 1.f / (float)max(end - beg, 1);
    store_bf16x4(out + (size_t)d * HDIM + lane * 4,
                 make_float4(a0 * c, a1 * c, a2 * c, a3 * c));
}

// ---------------------------------------------------------------------------
extern "C" void kernel_launch(void* const* d_in, const int* in_sizes, int n_in,
                              void* d_out, int out_size, void* d_ws, size_t ws_size,
                              hipStream_t stream)
{
    const float* x_tx      = (const float*)d_in[0];
    const float* x_addr    = (const float*)d_in[1];
    const int* addr_idx_at = (const int*)d_in[2];
    const int* tx_idx_at   = (const int*)d_in[3];
    const int* tx_idx_ta   = (const int*)d_in[4];
    const int* addr_idx_ta = (const int*)d_in[5];
    const float* w_in_tx   = (const float*)d_in[6];
    const float* b_in_tx   = (const float*)d_in[7];
    const float* w_in_addr = (const float*)d_in[8];
    const float* b_in_addr = (const float*)d_in[9];
    const float* w_at[2]  = {(const float*)d_in[10], (const float*)d_in[18]};
    const float* as_at[2] = {(const float*)d_in[11], (const float*)d_in[19]};
    const float* ad_at[2] = {(const float*)d_in[12], (const float*)d_in[20]};
    const float* b_at[2]  = {(const float*)d_in[13], (const float*)d_in[21]};
    const float* w_ta[2]  = {(const float*)d_in[14], (const float*)d_in[22]};
    const float* as_ta[2] = {(const float*)d_in[15], (const float*)d_in[23]};
    const float* ad_ta[2] = {(const float*)d_in[16], (const float*)d_in[24]};
    const float* b_ta[2]  = {(const float*)d_in[17], (const float*)d_in[25]};
    const float* ln_g_tx   = (const float*)d_in[26];
    const float* ln_b_tx   = (const float*)d_in[27];
    const float* ln_g_addr = (const float*)d_in[28];
    const float* ln_b_addr = (const float*)d_in[29];
    const float* w_out     = (const float*)d_in[30];
    const float* b_out     = (const float*)d_in[31];

    // ---- workspace carve-out (256B aligned) ----
    char* p = (char*)d_ws;
    auto alloc = [&](size_t bytes) -> void* {
        void* r = (void*)p; p += (bytes + 255) & ~(size_t)255; return r;
    };
    bf16* h0_tx   = (bf16*)alloc((size_t)NTX * 64 * 2);
    bf16* h0_addr = (bf16*)alloc((size_t)NADDR * 64 * 2);
    bf16* h_tx    = (bf16*)alloc((size_t)NTX * HDIM * 2);
    bf16* h_addr  = (bf16*)alloc((size_t)NADDR * HDIM * 2);
    bf16* hs_a    = (bf16*)alloc((size_t)NADDR * HDIM * 2);
    bf16* hs_t    = (bf16*)alloc((size_t)NTX * HDIM * 2);   // also pooled buffer
    float* al_src_at = (float*)alloc((size_t)NADDR * 4 * 4);
    float* al_dst_at = (float*)alloc((size_t)NTX * 4 * 4);
    float* al_src_ta = (float*)alloc((size_t)NTX * 4 * 4);
    float* al_dst_ta = (float*)alloc((size_t)NADDR * 4 * 4);
    float* Vd_at  = (float*)alloc(HDIM * 4 * 4);
    float* Vd_ta  = (float*)alloc(HDIM * 4 * 4);
    int* rp_at    = (int*)alloc((size_t)(NTX + 1) * 4);
    int* rp_ta    = (int*)alloc((size_t)(NADDR + 1) * 4);
    int* perm_at  = (int*)alloc((size_t)NEDGE * 4);
    int* perm_ta  = (int*)alloc((size_t)NEDGE * 4);
    int* deg_tx   = (int*)alloc((size_t)NTX * 4);
    int* deg_addr = (int*)alloc((size_t)NADDR * 4);
    int* cur_tx   = (int*)alloc((size_t)NTX * 4);
    int* cur_addr = (int*)alloc((size_t)NADDR * 4);
    int* bsum_tx  = (int*)alloc(1024 * 4);
    int* bsum_ad  = (int*)alloc(1024 * 4);
    // transposed bf16 weights: Wt[n][k]
    bf16* wt_at[2], *wt_ta[2], *wt_out;
    wt_at[0] = (bf16*)alloc((size_t)64 * HDIM * 2);
    wt_ta[0] = (bf16*)alloc((size_t)64 * HDIM * 2);
    wt_at[1] = (bf16*)alloc((size_t)HDIM * HDIM * 2);
    wt_ta[1] = (bf16*)alloc((size_t)HDIM * HDIM * 2);
    wt_out   = (bf16*)alloc((size_t)HDIM * HDIM * 2);

    dim3 blk(256);
    const int EG = (NEDGE + 255) / 256;
    auto gemm_fb = [&](const float* A, const float* B, const float* bias, bf16* C,
                       int M, int N, int K) {
        dim3 grid((M + 63) / 64, N / 64);
        hipLaunchKernelGGL((gemm_t<float, bf16>), grid, blk, 0, stream, A, B, bias, C, M, N, K);
    };
    auto mfma = [&](const bf16* A, const bf16* Wt, const float* bias, bf16* C,
                    int M, int K) {
        dim3 grid((M + 127) / 128, HDIM / 128);
        hipLaunchKernelGGL((gemm_mfma<bf16>), grid, blk, 0, stream, A, Wt, bias, C, M, HDIM, K);
    };

    // ---- weight transpose+convert (tiny) ----
    hipLaunchKernelGGL(transpose_w, dim3((64 * HDIM + 255) / 256), blk, 0, stream,
                       w_at[0], wt_at[0], 64, HDIM);
    hipLaunchKernelGGL(transpose_w, dim3((64 * HDIM + 255) / 256), blk, 0, stream,
                       w_ta[0], wt_ta[0], 64, HDIM);
    hipLaunchKernelGGL(transpose_w, dim3((HDIM * HDIM + 255) / 256), blk, 0, stream,
                       w_at[1], wt_at[1], HDIM, HDIM);
    hipLaunchKernelGGL(transpose_w, dim3((HDIM * HDIM + 255) / 256), blk, 0, stream,
                       w_ta[1], wt_ta[1], HDIM, HDIM);
    hipLaunchKernelGGL(transpose_w, dim3((HDIM * HDIM + 255) / 256), blk, 0, stream,
                       w_out, wt_out, HDIM, HDIM);

    // ---- CSR build for both relations ----
    hipMemsetAsync(deg_tx, 0, (size_t)NTX * 4, stream);
    hipMemsetAsync(deg_addr, 0, (size_t)NADDR * 4, stream);
    hipMemsetAsync(cur_tx, 0, (size_t)NTX * 4, stream);
    hipMemsetAsync(cur_addr, 0, (size_t)NADDR * 4, stream);
    hipLaunchKernelGGL(k_hist, dim3(EG), blk, 0, stream, tx_idx_at, deg_tx, NEDGE);
    hipLaunchKernelGGL(k_hist, dim3(EG), blk, 0, stream, addr_idx_ta, deg_addr, NEDGE);
    const int NB_tx = (NTX + 1023) / 1024, NB_ad = (NADDR + 1023) / 1024;
    hipLaunchKernelGGL(scan_partial, dim3(NB_tx), blk, 0, stream, deg_tx, bsum_tx, NTX);
    hipLaunchKernelGGL(scan_partial, dim3(NB_ad), blk, 0, stream, deg_addr, bsum_ad, NADDR);
    hipLaunchKernelGGL(scan_bsum, dim3(1), blk, 0, stream, bsum_tx, NB_tx, rp_at, NTX, NEDGE);
    hipLaunchKernelGGL(scan_bsum, dim3(1), blk, 0, stream, bsum_ad, NB_ad, rp_ta, NADDR, NEDGE);
    hipLaunchKernelGGL(scan_write, dim3(NB_tx), blk, 0, stream, deg_tx, bsum_tx, rp_at, NTX);
    hipLaunchKernelGGL(scan_write, dim3(NB_ad), blk, 0, stream, deg_addr, bsum_ad, rp_ta, NADDR);
    hipLaunchKernelGGL(k_scatter, dim3(EG), blk, 0, stream, tx_idx_at, rp_at, cur_tx, perm_at, NEDGE);
    hipLaunchKernelGGL(k_scatter, dim3(EG), blk, 0, stream, addr_idx_ta, rp_ta, cur_addr, perm_ta, NEDGE);

    // ---- input projections (fp32 path) ----
    gemm_fb(x_tx, w_in_tx, b_in_tx, h0_tx, NTX, 64, FTX);
    gemm_fb(x_addr, w_in_addr, b_in_addr, h0_addr, NADDR, 64, 64);

    for (int layer = 0; layer < 2; ++layer) {
        const int in_dim = layer ? HDIM : 64;
        const bf16* ftx = layer ? h_tx : h0_tx;
        const bf16* fad = layer ? h_addr : h0_addr;

        // projections for both relations (MFMA)
        mfma(fad, wt_at[layer], nullptr, hs_a, NADDR, in_dim);
        mfma(ftx, wt_ta[layer], nullptr, hs_t, NTX, in_dim);

        // attention logit halves
        hipLaunchKernelGGL(build_vd, dim3((in_dim * 4 + 255) / 256), blk, 0, stream,
                           w_at[layer], ad_at[layer], Vd_at, in_dim);
        hipLaunchKernelGGL(build_vd, dim3((in_dim * 4 + 255) / 256), blk, 0, stream,
                           w_ta[layer], ad_ta[layer], Vd_ta, in_dim);
        hipLaunchKernelGGL(attn_src, dim3((NADDR + 3) / 4), blk, 0, stream,
                           hs_a, as_at[layer], al_src_at, NADDR);
        hipLaunchKernelGGL(attn_src, dim3((NTX + 3) / 4), blk, 0, stream,
                           hs_t, as_ta[layer], al_src_ta, NTX);
        hipLaunchKernelGGL(attn_dst, dim3((NTX + 3) / 4), blk, 0, stream,
                           ftx, Vd_at, al_dst_at, NTX, in_dim);
        hipLaunchKernelGGL(attn_dst, dim3((NADDR + 3) / 4), blk, 0, stream,
                           fad, Vd_ta, al_dst_ta, NADDR, in_dim);

        // fused aggregate + bias + LN + residual + ELU (in-place h update)
        const bf16* res_tx = layer ? h_tx : nullptr;
        const bf16* res_ad = layer ? h_addr : nullptr;
        hipLaunchKernelGGL(aggregate_ln_elu, dim3((NTX + 3) / 4), blk, 0, stream,
                           rp_at, perm_at, addr_idx_at, al_src_at, al_dst_at, hs_a,
                           b_at[layer], ln_g_tx, ln_b_tx, res_tx, h_tx, NTX);
        hipLaunchKernelGGL(aggregate_ln_elu, dim3((NADDR + 3) / 4), blk, 0, stream,
                           rp_ta, perm_ta, tx_idx_ta, al_src_ta, al_dst_ta, hs_t,
                           b_ta[layer], ln_g_addr, ln_b_addr, res_ad, h_addr, NADDR);
    }

    // ---- scatter-mean pooling (reuse at-CSR) + output projection (MFMA) ----
    hipLaunchKernelGGL(k_pool, dim3((NTX + 3) / 4), blk, 0, stream,
                       rp_at, perm_at, addr_idx_at, h_addr, hs_t, NTX);
    {
        dim3 grid((NTX + 127) / 128, HDIM / 128);
        hipLaunchKernelGGL((gemm_mfma<float>), grid, blk, 0, stream,
                           hs_t, wt_out, b_out, (float*)d_out, NTX, HDIM, HDIM);
    }
}

// Round 4
// 1501.894 us; speedup vs baseline: 1.6361x; 1.1055x over previous
//
#include <hip/hip_runtime.h>
#include <hip/hip_bf16.h>

#define NTX    100000
#define NADDR  200000
#define NEDGE  400000
#define FTX    165
#define HDIM   256
#define NEG_SLOPE 0.2f
#define LN_EPS 1e-5f

typedef __hip_bfloat16 bf16;
typedef __attribute__((ext_vector_type(8))) short short8;   // 8 bf16 = 4 VGPRs
typedef __attribute__((ext_vector_type(4))) float floatx4;

__device__ __forceinline__ float to_f(float x) { return x; }
__device__ __forceinline__ float to_f(bf16 x) { return __bfloat162float(x); }
__device__ __forceinline__ void from_f(float x, float& o) { o = x; }
__device__ __forceinline__ void from_f(float x, bf16& o) { o = __float2bfloat16(x); }

__device__ __forceinline__ float4 load_bf16x4(const bf16* p) {
    const __hip_bfloat162* q = (const __hip_bfloat162*)p;
    __hip_bfloat162 v0 = q[0], v1 = q[1];
    return make_float4(__bfloat162float(v0.x), __bfloat162float(v0.y),
                       __bfloat162float(v1.x), __bfloat162float(v1.y));
}
__device__ __forceinline__ void store_bf16x4(bf16* p, float4 v) {
    __hip_bfloat162* q = (__hip_bfloat162*)p;
    __hip_bfloat162 t0, t1;
    t0.x = __float2bfloat16(v.x); t0.y = __float2bfloat16(v.y);
    t1.x = __float2bfloat16(v.z); t1.y = __float2bfloat16(v.w);
    q[0] = t0; q[1] = t1;
}

// ---------------------------------------------------------------------------
// fp32 SIMD GEMM (in-projections only). 64x64 tile, BK=16, 4x4 microtile.
// ---------------------------------------------------------------------------
template<typename TA, typename TC>
__global__ __launch_bounds__(256) void gemm_t(
    const TA* __restrict__ A, const float* __restrict__ B,
    const float* __restrict__ bias, TC* __restrict__ C,
    int M, int N, int K)
{
    __shared__ float As[16][64];
    __shared__ float Bs[16][64];
    const int t = threadIdx.x;
    const int row0 = blockIdx.x * 64;
    const int col0 = blockIdx.y * 64;
    const int tm = t >> 4, tn = t & 15;
    float acc[4][4] = {};
    for (int k0 = 0; k0 < K; k0 += 16) {
#pragma unroll
        for (int i = 0; i < 4; ++i) {
            int idx = t + 256 * i;
            int m = idx >> 4, kk = idx & 15;
            int r = row0 + m, c = k0 + kk;
            As[kk][m] = (r < M && c < K) ? to_f(A[(size_t)r * K + c]) : 0.f;
        }
#pragma unroll
        for (int i = 0; i < 4; ++i) {
            int idx = t + 256 * i;
            int kk = idx >> 6, n = idx & 63;
            int r = k0 + kk;
            Bs[kk][n] = (r < K) ? B[(size_t)r * N + col0 + n] : 0.f;
        }
        __syncthreads();
#pragma unroll
        for (int kk = 0; kk < 16; ++kk) {
            const float4 a4 = *(const float4*)&As[kk][tm * 4];
            const float4 b4 = *(const float4*)&Bs[kk][tn * 4];
            float a_[4] = {a4.x, a4.y, a4.z, a4.w};
            float b_[4] = {b4.x, b4.y, b4.z, b4.w};
#pragma unroll
            for (int i = 0; i < 4; ++i)
#pragma unroll
                for (int j = 0; j < 4; ++j)
                    acc[i][j] += a_[i] * b_[j];
        }
        __syncthreads();
    }
    float4 bv = make_float4(0.f, 0.f, 0.f, 0.f);
    if (bias) bv = *(const float4*)&bias[col0 + tn * 4];
#pragma unroll
    for (int i = 0; i < 4; ++i) {
        int r = row0 + tm * 4 + i;
        if (r < M) {
            TC* cp = &C[(size_t)r * N + col0 + tn * 4];
            from_f(acc[i][0] + bv.x, cp[0]);
            from_f(acc[i][1] + bv.y, cp[1]);
            from_f(acc[i][2] + bv.z, cp[2]);
            from_f(acc[i][3] + bv.w, cp[3]);
        }
    }
}

// ---------------------------------------------------------------------------
// Wt[n,k] = bf16(W[k,n])  (one-time weight transpose+convert)
// ---------------------------------------------------------------------------
__global__ void transpose_w(const float* __restrict__ W, bf16* __restrict__ Wt,
                            int K, int N)
{
    int idx = blockIdx.x * blockDim.x + threadIdx.x;
    if (idx >= K * N) return;
    int k = idx / N, n = idx - k * N;
    Wt[(size_t)n * K + k] = __float2bfloat16(W[idx]);
}

// ---------------------------------------------------------------------------
// MFMA bf16 GEMM: C[M,N] = A[M,K] @ Wt[N,K]^T (+bias).
// 128x128 block tile, BK=32, 256 thr = 4 waves (2x2), each wave 64x64.
// ---------------------------------------------------------------------------
template<typename TC>
__global__ __launch_bounds__(256) void gemm_mfma(
    const bf16* __restrict__ A, const bf16* __restrict__ Wt,
    const float* __restrict__ bias, TC* __restrict__ C,
    int M, int N, int K)
{
    __shared__ __align__(16) bf16 As[128][40];   // +8 pad: 2-way LDS conflicts only
    __shared__ __align__(16) bf16 Bs[128][40];
    const int t = threadIdx.x;
    const int wv = t >> 6, lane = t & 63;
    const int l15 = lane & 15, quad = lane >> 4;
    const int row0 = blockIdx.x * 128;
    const int col0 = blockIdx.y * 128;
    const int wrow = (wv >> 1) * 64, wcol = (wv & 1) * 64;

    floatx4 acc[4][4] = {};

    for (int k0 = 0; k0 < K; k0 += 32) {
#pragma unroll
        for (int i = 0; i < 2; ++i) {
            int idx = t + 256 * i;            // 0..511
            int r = idx >> 2, c = (idx & 3) * 8;
            uint4 va = make_uint4(0, 0, 0, 0);
            if (row0 + r < M) va = *(const uint4*)&A[(size_t)(row0 + r) * K + k0 + c];
            *(uint4*)&As[r][c] = va;
            uint4 vb = make_uint4(0, 0, 0, 0);
            if (col0 + r < N) vb = *(const uint4*)&Wt[(size_t)(col0 + r) * K + k0 + c];
            *(uint4*)&Bs[r][c] = vb;
        }
        __syncthreads();
        short8 af[4], bfr[4];
#pragma unroll
        for (int rb = 0; rb < 4; ++rb)
            af[rb] = *(const short8*)&As[wrow + rb * 16 + l15][quad * 8];
#pragma unroll
        for (int nb = 0; nb < 4; ++nb)
            bfr[nb] = *(const short8*)&Bs[wcol + nb * 16 + l15][quad * 8];
#pragma unroll
        for (int rb = 0; rb < 4; ++rb)
#pragma unroll
            for (int nb = 0; nb < 4; ++nb)
                acc[rb][nb] = __builtin_amdgcn_mfma_f32_16x16x32_bf16(
                    af[rb], bfr[nb], acc[rb][nb], 0, 0, 0);
        __syncthreads();
    }

#pragma unroll
    for (int rb = 0; rb < 4; ++rb)
#pragma unroll
        for (int nb = 0; nb < 4; ++nb) {
            int col = col0 + wcol + nb * 16 + l15;
            float bv = bias ? bias[col] : 0.f;
#pragma unroll
            for (int r = 0; r < 4; ++r) {
                int row = row0 + wrow + rb * 16 + quad * 4 + r;
                if (row < M)
                    from_f(acc[rb][nb][r] + bv, C[(size_t)row * N + col]);
            }
        }
}

// ---------------------------------------------------------------------------
// Vd[k,h] = sum_j W[k, h*64+j] * a_d[h,j]
// ---------------------------------------------------------------------------
__global__ void build_vd(const float* __restrict__ W, const float* __restrict__ a_d,
                         float* __restrict__ Vd, int K)
{
    int idx = blockIdx.x * blockDim.x + threadIdx.x;  // k*4+h
    if (idx >= K * 4) return;
    int k = idx >> 2, h = idx & 3;
    float d = 0.f;
    for (int j = 0; j < 64; ++j)
        d += W[(size_t)k * HDIM + h * 64 + j] * a_d[h * 64 + j];
    Vd[idx] = d;
}

// ---------------------------------------------------------------------------
// al_dst[n,h] = sum_k X[n,k] * V[k,h].  Wave per row, bf16x4 loads.
// ---------------------------------------------------------------------------
__global__ __launch_bounds__(256) void attn_dst(
    const bf16* __restrict__ X, const float* __restrict__ V,
    float* __restrict__ out, int M, int K)
{
    int n = (blockIdx.x * 256 + threadIdx.x) >> 6;
    int lane = threadIdx.x & 63;
    if (n >= M) return;
    const bf16* xr = X + (size_t)n * K;
    float a0 = 0.f, a1 = 0.f, a2 = 0.f, a3 = 0.f;
    for (int k0 = lane * 4; k0 < K; k0 += 256) {
        float4 x = load_bf16x4(xr + k0);
        float xv[4] = {x.x, x.y, x.z, x.w};
#pragma unroll
        for (int j = 0; j < 4; ++j) {
            const float4 v = *(const float4*)&V[(k0 + j) * 4];
            a0 += xv[j] * v.x; a1 += xv[j] * v.y;
            a2 += xv[j] * v.z; a3 += xv[j] * v.w;
        }
    }
#pragma unroll
    for (int off = 32; off; off >>= 1) {
        a0 += __shfl_xor(a0, off); a1 += __shfl_xor(a1, off);
        a2 += __shfl_xor(a2, off); a3 += __shfl_xor(a3, off);
    }
    if (lane == 0) {
        out[(size_t)n * 4 + 0] = a0; out[(size_t)n * 4 + 1] = a1;
        out[(size_t)n * 4 + 2] = a2; out[(size_t)n * 4 + 3] = a3;
    }
}

// ---------------------------------------------------------------------------
// al_src[n,h] = sum_j hs[n, h*64+j] * a_s[h,j].  Wave per row (hs 256-wide).
// ---------------------------------------------------------------------------
__global__ __launch_bounds__(256) void attn_src(
    const bf16* __restrict__ hs, const float* __restrict__ a_s,
    float* __restrict__ out, int M)
{
    int n = (blockIdx.x * 256 + threadIdx.x) >> 6;
    int lane = threadIdx.x & 63;
    if (n >= M) return;
    float4 v = load_bf16x4(hs + (size_t)n * HDIM + lane * 4);
    float4 a = *(const float4*)&a_s[lane * 4];
    float s = v.x * a.x + v.y * a.y + v.z * a.z + v.w * a.w;
#pragma unroll
    for (int off = 1; off < 16; off <<= 1) s += __shfl_xor(s, off);
    if ((lane & 15) == 0) out[(size_t)n * 4 + (lane >> 4)] = s;
}

// ---------------------------------------------------------------------------
// CSR build: histogram, 3-phase exclusive scan, scatter (writes csr_src/dst).
// ---------------------------------------------------------------------------
__global__ void k_hist(const int* __restrict__ dst, int* __restrict__ deg, int E)
{
    int e = blockIdx.x * blockDim.x + threadIdx.x;
    if (e < E) atomicAdd(&deg[dst[e]], 1);
}

__global__ void scan_partial(const int* __restrict__ deg, int* __restrict__ bsum, int N)
{
    __shared__ int lds[256];
    int base = blockIdx.x * 1024, t = threadIdx.x;
    int s = 0;
#pragma unroll
    for (int i = 0; i < 4; ++i) {
        int idx = base + t * 4 + i;
        if (idx < N) s += deg[idx];
    }
    lds[t] = s; __syncthreads();
    for (int off = 128; off; off >>= 1) {
        if (t < off) lds[t] += lds[t + off];
        __syncthreads();
    }
    if (t == 0) bsum[blockIdx.x] = lds[0];
}

__global__ void scan_bsum(int* __restrict__ bsum, int NB, int* __restrict__ rp, int N, int E)
{
    if (threadIdx.x == 0 && blockIdx.x == 0) {
        int acc = 0;
        for (int b = 0; b < NB; ++b) { int v = bsum[b]; bsum[b] = acc; acc += v; }
        rp[N] = E;
    }
}

__global__ void scan_write(const int* __restrict__ deg, const int* __restrict__ bsum,
                           int* __restrict__ rp, int N)
{
    __shared__ int lds[256];
    int base = blockIdx.x * 1024, t = threadIdx.x;
    int v[4]; int s = 0;
#pragma unroll
    for (int i = 0; i < 4; ++i) {
        int idx = base + t * 4 + i;
        v[i] = (idx < N) ? deg[idx] : 0;
        s += v[i];
    }
    lds[t] = s; __syncthreads();
    for (int off = 1; off < 256; off <<= 1) {
        int x = (t >= off) ? lds[t - off] : 0;
        __syncthreads();
        lds[t] += x;
        __syncthreads();
    }
    int excl = lds[t] - s + bsum[blockIdx.x];
#pragma unroll
    for (int i = 0; i < 4; ++i) {
        int idx = base + t * 4 + i;
        if (idx < N) rp[idx] = excl;
        excl += v[i];
    }
}

__global__ void k_scatter(const int* __restrict__ src, const int* __restrict__ dst,
                          const int* __restrict__ rp, int* __restrict__ cur,
                          int* __restrict__ csr_src, int* __restrict__ csr_dst, int E)
{
    int e = blockIdx.x * blockDim.x + threadIdx.x;
    if (e >= E) return;
    int d = dst[e];
    int pos = atomicAdd(&cur[d], 1);
    int p = rp[d] + pos;
    csr_src[p] = src[e];
    csr_dst[p] = d;
}

// ---------------------------------------------------------------------------
// Edge-parallel: ex_csr[i][h] = exp(leaky(al_src[csr_src[i]][h] + al_dst[csr_dst[i]][h]))
// ---------------------------------------------------------------------------
__global__ void edge_ex(const int* __restrict__ csr_src, const int* __restrict__ csr_dst,
                        const float* __restrict__ al_src, const float* __restrict__ al_dst,
                        float* __restrict__ ex_csr, int E)
{
    int i = blockIdx.x * blockDim.x + threadIdx.x;
    if (i >= E) return;
    int s = csr_src[i], d = csr_dst[i];
    float4 as4 = *(const float4*)&al_src[(size_t)s * 4];
    float4 ad4 = *(const float4*)&al_dst[(size_t)d * 4];
    float l[4] = {as4.x + ad4.x, as4.y + ad4.y, as4.z + ad4.z, as4.w + ad4.w};
    float4 o;
    float* op = (float*)&o;
#pragma unroll
    for (int h = 0; h < 4; ++h) {
        float v = l[h] >= 0.f ? l[h] : NEG_SLOPE * l[h];
        op[h] = __expf(v);
    }
    *(float4*)&ex_csr[(size_t)i * 4] = o;
}

// ---------------------------------------------------------------------------
// Fused per-dst-node: softmax-weighted gather (CSR, precomputed ex) + bias
// + LayerNorm (+residual) + ELU -> h_out (bf16). Wave per node, 2x unrolled.
// ---------------------------------------------------------------------------
__global__ __launch_bounds__(256) void aggregate_ln_elu(
    const int* __restrict__ rp, const int* __restrict__ csr_src,
    const float* __restrict__ ex_csr, const bf16* __restrict__ hs,
    const float* __restrict__ bias, const float* __restrict__ g,
    const float* __restrict__ b,
    const bf16* __restrict__ res, bf16* __restrict__ h_out, int n_dst)
{
    int d = (blockIdx.x * 256 + threadIdx.x) >> 6;
    int lane = threadIdx.x & 63;
    if (d >= n_dst) return;
    int head = lane >> 4;
    int beg = rp[d], end = rp[d + 1];
    float acc0 = 0.f, acc1 = 0.f, acc2 = 0.f, acc3 = 0.f, den = 0.f;
    int i = beg;
    for (; i + 2 <= end; i += 2) {
        int s0 = csr_src[i], s1 = csr_src[i + 1];
        float e0 = ex_csr[(size_t)i * 4 + head];
        float e1 = ex_csr[(size_t)(i + 1) * 4 + head];
        float4 v0 = load_bf16x4(hs + (size_t)s0 * HDIM + lane * 4);
        float4 v1 = load_bf16x4(hs + (size_t)s1 * HDIM + lane * 4);
        den += e0 + e1;
        acc0 += e0 * v0.x + e1 * v1.x;
        acc1 += e0 * v0.y + e1 * v1.y;
        acc2 += e0 * v0.z + e1 * v1.z;
        acc3 += e0 * v0.w + e1 * v1.w;
    }
    if (i < end) {
        int s0 = csr_src[i];
        float e0 = ex_csr[(size_t)i * 4 + head];
        float4 v0 = load_bf16x4(hs + (size_t)s0 * HDIM + lane * 4);
        den += e0;
        acc0 += e0 * v0.x; acc1 += e0 * v0.y;
        acc2 += e0 * v0.z; acc3 += e0 * v0.w;
    }
    float inv = den > 0.f ? 1.f / den : 0.f;
    float4 bi = *(const float4*)&bias[lane * 4];
    float x0 = acc0 * inv + bi.x, x1 = acc1 * inv + bi.y;
    float x2 = acc2 * inv + bi.z, x3 = acc3 * inv + bi.w;
    float sum = x0 + x1 + x2 + x3;
#pragma unroll
    for (int off = 32; off; off >>= 1) sum += __shfl_xor(sum, off);
    float mu = sum * (1.f / 256.f);
    float d0 = x0 - mu, d1 = x1 - mu, d2 = x2 - mu, d3 = x3 - mu;
    float sq = d0 * d0 + d1 * d1 + d2 * d2 + d3 * d3;
#pragma unroll
    for (int off = 32; off; off >>= 1) sq += __shfl_xor(sq, off);
    float rstd = rsqrtf(sq * (1.f / 256.f) + LN_EPS);
    float4 gg = *(const float4*)&g[lane * 4];
    float4 bb = *(const float4*)&b[lane * 4];
    float y0 = d0 * rstd * gg.x + bb.x;
    float y1 = d1 * rstd * gg.y + bb.y;
    float y2 = d2 * rstd * gg.z + bb.z;
    float y3 = d3 * rstd * gg.w + bb.w;
    if (res) {
        float4 r4 = load_bf16x4(res + (size_t)d * HDIM + lane * 4);
        y0 += r4.x; y1 += r4.y; y2 += r4.z; y3 += r4.w;
    }
    float4 o;
    o.x = y0 > 0.f ? y0 : expm1f(y0);
    o.y = y1 > 0.f ? y1 : expm1f(y1);
    o.z = y2 > 0.f ? y2 : expm1f(y2);
    o.w = y3 > 0.f ? y3 : expm1f(y3);
    store_bf16x4(h_out + (size_t)d * HDIM + lane * 4, o);
}

// ---------------------------------------------------------------------------
// Pool: mean over incoming at-edges of h_addr -> pooled (bf16). Wave per node.
// ---------------------------------------------------------------------------
__global__ __launch_bounds__(256) void k_pool(
    const int* __restrict__ rp, const int* __restrict__ csr_src,
    const bf16* __restrict__ h, bf16* __restrict__ out, int n_dst)
{
    int d = (blockIdx.x * 256 + threadIdx.x) >> 6;
    int lane = threadIdx.x & 63;
    if (d >= n_dst) return;
    int beg = rp[d], end = rp[d + 1];
    float a0 = 0.f, a1 = 0.f, a2 = 0.f, a3 = 0.f;
    int i = beg;
    for (; i + 2 <= end; i += 2) {
        int s0 = csr_src[i], s1 = csr_src[i + 1];
        float4 v0 = load_bf16x4(h + (size_t)s0 * HDIM + lane * 4);
        float4 v1 = load_bf16x4(h + (size_t)s1 * HDIM + lane * 4);
        a0 += v0.x + v1.x; a1 += v0.y + v1.y;
        a2 += v0.z + v1.z; a3 += v0.w + v1.w;
    }
    if (i < end) {
        float4 v = load_bf16x4(h + (size_t)csr_src[i] * HDIM + lane * 4);
        a0 += v.x; a1 += v.y; a2 += v.z; a3 += v.w;
    }
    float c = 1.f / (float)max(end - beg, 1);
    store_bf16x4(out + (size_t)d * HDIM + lane * 4,
                 make_float4(a0 * c, a1 * c, a2 * c, a3 * c));
}

// ---------------------------------------------------------------------------
extern "C" void kernel_launch(void* const* d_in, const int* in_sizes, int n_in,
                              void* d_out, int out_size, void* d_ws, size_t ws_size,
                              hipStream_t stream)
{
    const float* x_tx      = (const float*)d_in[0];
    const float* x_addr    = (const float*)d_in[1];
    const int* addr_idx_at = (const int*)d_in[2];
    const int* tx_idx_at   = (const int*)d_in[3];
    const int* tx_idx_ta   = (const int*)d_in[4];
    const int* addr_idx_ta = (const int*)d_in[5];
    const float* w_in_tx   = (const float*)d_in[6];
    const float* b_in_tx   = (const float*)d_in[7];
    const float* w_in_addr = (const float*)d_in[8];
    const float* b_in_addr = (const float*)d_in[9];
    const float* w_at[2]  = {(const float*)d_in[10], (const float*)d_in[18]};
    const float* as_at[2] = {(const float*)d_in[11], (const float*)d_in[19]};
    const float* ad_at[2] = {(const float*)d_in[12], (const float*)d_in[20]};
    const float* b_at[2]  = {(const float*)d_in[13], (const float*)d_in[21]};
    const float* w_ta[2]  = {(const float*)d_in[14], (const float*)d_in[22]};
    const float* as_ta[2] = {(const float*)d_in[15], (const float*)d_in[23]};
    const float* ad_ta[2] = {(const float*)d_in[16], (const float*)d_in[24]};
    const float* b_ta[2]  = {(const float*)d_in[17], (const float*)d_in[25]};
    const float* ln_g_tx   = (const float*)d_in[26];
    const float* ln_b_tx   = (const float*)d_in[27];
    const float* ln_g_addr = (const float*)d_in[28];
    const float* ln_b_addr = (const float*)d_in[29];
    const float* w_out     = (const float*)d_in[30];
    const float* b_out     = (const float*)d_in[31];

    // ---- workspace carve-out (256B aligned) ----
    char* p = (char*)d_ws;
    auto alloc = [&](size_t bytes) -> void* {
        void* r = (void*)p; p += (bytes + 255) & ~(size_t)255; return r;
    };
    bf16* h0_tx   = (bf16*)alloc((size_t)NTX * 64 * 2);
    bf16* h0_addr = (bf16*)alloc((size_t)NADDR * 64 * 2);
    bf16* h_tx    = (bf16*)alloc((size_t)NTX * HDIM * 2);
    bf16* h_addr  = (bf16*)alloc((size_t)NADDR * HDIM * 2);
    bf16* hs_a    = (bf16*)alloc((size_t)NADDR * HDIM * 2);
    bf16* hs_t    = (bf16*)alloc((size_t)NTX * HDIM * 2);   // also pooled buffer
    float* al_src_at = (float*)alloc((size_t)NADDR * 4 * 4);
    float* al_dst_at = (float*)alloc((size_t)NTX * 4 * 4);
    float* al_src_ta = (float*)alloc((size_t)NTX * 4 * 4);
    float* al_dst_ta = (float*)alloc((size_t)NADDR * 4 * 4);
    float* Vd_at  = (float*)alloc(HDIM * 4 * 4);
    float* Vd_ta  = (float*)alloc(HDIM * 4 * 4);
    float* ex_csr = (float*)alloc((size_t)NEDGE * 4 * 4);
    int* rp_at    = (int*)alloc((size_t)(NTX + 1) * 4);
    int* rp_ta    = (int*)alloc((size_t)(NADDR + 1) * 4);
    int* csr_src_at = (int*)alloc((size_t)NEDGE * 4);
    int* csr_dst_at = (int*)alloc((size_t)NEDGE * 4);
    int* csr_src_ta = (int*)alloc((size_t)NEDGE * 4);
    int* csr_dst_ta = (int*)alloc((size_t)NEDGE * 4);
    int* deg_tx   = (int*)alloc((size_t)NTX * 4);
    int* deg_addr = (int*)alloc((size_t)NADDR * 4);
    int* cur_tx   = (int*)alloc((size_t)NTX * 4);
    int* cur_addr = (int*)alloc((size_t)NADDR * 4);
    int* bsum_tx  = (int*)alloc(1024 * 4);
    int* bsum_ad  = (int*)alloc(1024 * 4);
    // transposed bf16 weights: Wt[n][k]
    bf16* wt_at[2], *wt_ta[2], *wt_out;
    wt_at[0] = (bf16*)alloc((size_t)64 * HDIM * 2);
    wt_ta[0] = (bf16*)alloc((size_t)64 * HDIM * 2);
    wt_at[1] = (bf16*)alloc((size_t)HDIM * HDIM * 2);
    wt_ta[1] = (bf16*)alloc((size_t)HDIM * HDIM * 2);
    wt_out   = (bf16*)alloc((size_t)HDIM * HDIM * 2);

    dim3 blk(256);
    const int EG = (NEDGE + 255) / 256;
    auto gemm_fb = [&](const float* A, const float* B, const float* bias, bf16* C,
                       int M, int N, int K) {
        dim3 grid((M + 63) / 64, N / 64);
        hipLaunchKernelGGL((gemm_t<float, bf16>), grid, blk, 0, stream, A, B, bias, C, M, N, K);
    };
    auto mfma = [&](const bf16* A, const bf16* Wt, const float* bias, bf16* C,
                    int M, int K) {
        dim3 grid((M + 127) / 128, HDIM / 128);
        hipLaunchKernelGGL((gemm_mfma<bf16>), grid, blk, 0, stream, A, Wt, bias, C, M, HDIM, K);
    };

    // ---- weight transpose+convert (tiny) ----
    hipLaunchKernelGGL(transpose_w, dim3((64 * HDIM + 255) / 256), blk, 0, stream,
                       w_at[0], wt_at[0], 64, HDIM);
    hipLaunchKernelGGL(transpose_w, dim3((64 * HDIM + 255) / 256), blk, 0, stream,
                       w_ta[0], wt_ta[0], 64, HDIM);
    hipLaunchKernelGGL(transpose_w, dim3((HDIM * HDIM + 255) / 256), blk, 0, stream,
                       w_at[1], wt_at[1], HDIM, HDIM);
    hipLaunchKernelGGL(transpose_w, dim3((HDIM * HDIM + 255) / 256), blk, 0, stream,
                       w_ta[1], wt_ta[1], HDIM, HDIM);
    hipLaunchKernelGGL(transpose_w, dim3((HDIM * HDIM + 255) / 256), blk, 0, stream,
                       w_out, wt_out, HDIM, HDIM);

    // ---- CSR build for both relations ----
    hipMemsetAsync(deg_tx, 0, (size_t)NTX * 4, stream);
    hipMemsetAsync(deg_addr, 0, (size_t)NADDR * 4, stream);
    hipMemsetAsync(cur_tx, 0, (size_t)NTX * 4, stream);
    hipMemsetAsync(cur_addr, 0, (size_t)NADDR * 4, stream);
    hipLaunchKernelGGL(k_hist, dim3(EG), blk, 0, stream, tx_idx_at, deg_tx, NEDGE);
    hipLaunchKernelGGL(k_hist, dim3(EG), blk, 0, stream, addr_idx_ta, deg_addr, NEDGE);
    const int NB_tx = (NTX + 1023) / 1024, NB_ad = (NADDR + 1023) / 1024;
    hipLaunchKernelGGL(scan_partial, dim3(NB_tx), blk, 0, stream, deg_tx, bsum_tx, NTX);
    hipLaunchKernelGGL(scan_partial, dim3(NB_ad), blk, 0, stream, deg_addr, bsum_ad, NADDR);
    hipLaunchKernelGGL(scan_bsum, dim3(1), blk, 0, stream, bsum_tx, NB_tx, rp_at, NTX, NEDGE);
    hipLaunchKernelGGL(scan_bsum, dim3(1), blk, 0, stream, bsum_ad, NB_ad, rp_ta, NADDR, NEDGE);
    hipLaunchKernelGGL(scan_write, dim3(NB_tx), blk, 0, stream, deg_tx, bsum_tx, rp_at, NTX);
    hipLaunchKernelGGL(scan_write, dim3(NB_ad), blk, 0, stream, deg_addr, bsum_ad, rp_ta, NADDR);
    hipLaunchKernelGGL(k_scatter, dim3(EG), blk, 0, stream,
                       addr_idx_at, tx_idx_at, rp_at, cur_tx, csr_src_at, csr_dst_at, NEDGE);
    hipLaunchKernelGGL(k_scatter, dim3(EG), blk, 0, stream,
                       tx_idx_ta, addr_idx_ta, rp_ta, cur_addr, csr_src_ta, csr_dst_ta, NEDGE);

    // ---- input projections (fp32 path) ----
    gemm_fb(x_tx, w_in_tx, b_in_tx, h0_tx, NTX, 64, FTX);
    gemm_fb(x_addr, w_in_addr, b_in_addr, h0_addr, NADDR, 64, 64);

    for (int layer = 0; layer < 2; ++layer) {
        const int in_dim = layer ? HDIM : 64;
        const bf16* ftx = layer ? h_tx : h0_tx;
        const bf16* fad = layer ? h_addr : h0_addr;

        // projections for both relations (MFMA)
        mfma(fad, wt_at[layer], nullptr, hs_a, NADDR, in_dim);
        mfma(ftx, wt_ta[layer], nullptr, hs_t, NTX, in_dim);

        // attention logit halves
        hipLaunchKernelGGL(build_vd, dim3((in_dim * 4 + 255) / 256), blk, 0, stream,
                           w_at[layer], ad_at[layer], Vd_at, in_dim);
        hipLaunchKernelGGL(build_vd, dim3((in_dim * 4 + 255) / 256), blk, 0, stream,
                           w_ta[layer], ad_ta[layer], Vd_ta, in_dim);
        hipLaunchKernelGGL(attn_src, dim3((NADDR + 3) / 4), blk, 0, stream,
                           hs_a, as_at[layer], al_src_at, NADDR);
        hipLaunchKernelGGL(attn_src, dim3((NTX + 3) / 4), blk, 0, stream,
                           hs_t, as_ta[layer], al_src_ta, NTX);
        hipLaunchKernelGGL(attn_dst, dim3((NTX + 3) / 4), blk, 0, stream,
                           ftx, Vd_at, al_dst_at, NTX, in_dim);
        hipLaunchKernelGGL(attn_dst, dim3((NADDR + 3) / 4), blk, 0, stream,
                           fad, Vd_ta, al_dst_ta, NADDR, in_dim);

        // ---- relation at: aggregate into tx ----
        const bf16* res_tx = layer ? h_tx : nullptr;
        const bf16* res_ad = layer ? h_addr : nullptr;
        hipLaunchKernelGGL(edge_ex, dim3(EG), blk, 0, stream,
                           csr_src_at, csr_dst_at, al_src_at, al_dst_at, ex_csr, NEDGE);
        hipLaunchKernelGGL(aggregate_ln_elu, dim3((NTX + 3) / 4), blk, 0, stream,
                           rp_at, csr_src_at, ex_csr, hs_a,
                           b_at[layer], ln_g_tx, ln_b_tx, res_tx, h_tx, NTX);
        // ---- relation ta: aggregate into addr ----
        hipLaunchKernelGGL(edge_ex, dim3(EG), blk, 0, stream,
                           csr_src_ta, csr_dst_ta, al_src_ta, al_dst_ta, ex_csr, NEDGE);
        hipLaunchKernelGGL(aggregate_ln_elu, dim3((NADDR + 3) / 4), blk, 0, stream,
                           rp_ta, csr_src_ta, ex_csr, hs_t,
                           b_ta[layer], ln_g_addr, ln_b_addr, res_ad, h_addr, NADDR);
    }

    // ---- scatter-mean pooling (reuse at-CSR) + output projection (MFMA) ----
    hipLaunchKernelGGL(k_pool, dim3((NTX + 3) / 4), blk, 0, stream,
                       rp_at, csr_src_at, h_addr, hs_t, NTX);
    {
        dim3 grid((NTX + 127) / 128, HDIM / 128);
        hipLaunchKernelGGL((gemm_mfma<float>), grid, blk, 0, stream,
                           hs_t, wt_out, b_out, (float*)d_out, NTX, HDIM, HDIM);
    }
}